// Round 1
// 478.501 us; speedup vs baseline: 1.0724x; 1.0724x over previous
//
#include <hip/hip_runtime.h>

// Fused 4-scale starlet transform: ONE kernel, whole cascade in LDS.
// - 64x64 output tile per block, halo 32 (cumulative radius 30, rounded to vec4).
// - Region 128x128 floats in LDS buffer A (coarse, updated in place per scale);
//   buffer B holds the horizontal-pass intermediate (htmp).
// - float4 global + LDS accesses throughout; 4-row register blocking in v-pass.
// - HBM traffic: 64 MiB read + 320 MiB write (vs 768 MiB for the 4-launch version).

constexpr int H  = 1024, W = 1024;
constexpr int TS = 64;          // output tile
constexpr int HALO = 32;        // >= 2*(1+2+4+8) = 30, vec4-aligned
constexpr int RW = 128;         // region = TS + 2*HALO
constexpr int LSV = 33;         // LDS row stride in float4 (132 floats: +4 pad)
constexpr int NT = 1024;        // threads per block

static_assert(2 * RW * LSV * 16 <= 160 * 1024, "LDS budget");

__device__ __forceinline__ int reflect_i(int g, int n) {
    g = (g < 0) ? -g : g;
    return (g >= n) ? (2 * n - 2 - g) : g;
}

template<int D>
__device__ __forceinline__ void scale_pass(float4* __restrict__ A4, float4* __restrict__ B4,
                                           int tid, int bx, int by,
                                           float* __restrict__ det, float* __restrict__ coa)
{
    const float k0 = 0.0625f, k1 = 0.25f, k2 = 0.375f;
    constexpr int Q  = 32 - 2 * D;       // vec4 columns per row this scale
    constexpr int HR = RW - 4 * D;       // htmp rows: [2D, 128-2D)
    constexpr int HTASKS = HR * Q;

    // ---- horizontal 5-tap (dilated): A -> B ----
    for (int t = tid; t < HTASKS; t += NT) {
        int r    = 2 * D + t / Q;
        int qx   = D + t % Q;            // x = 4*qx, x in [4D, 128-4D)
        int base = r * LSV + qx;
        float4 o;
        if constexpr (D >= 4) {
            // taps at x + (j-2)*D are vec4-aligned for D=4,8
            float4 t0 = A4[base - D / 2];
            float4 t1 = A4[base - D / 4];
            float4 t2 = A4[base];
            float4 t3 = A4[base + D / 4];
            float4 t4 = A4[base + D / 2];
            o.x = k0 * (t0.x + t4.x) + k1 * (t1.x + t3.x) + k2 * t2.x;
            o.y = k0 * (t0.y + t4.y) + k1 * (t1.y + t3.y) + k2 * t2.y;
            o.z = k0 * (t0.z + t4.z) + k1 * (t1.z + t3.z) + k2 * t2.z;
            o.w = k0 * (t0.w + t4.w) + k1 * (t1.w + t3.w) + k2 * t2.w;
        } else {
            // span [x-4, x+8) covers taps for D=1 (x±2) and D=2 (x±4)
            float4 v0 = A4[base - 1], v1 = A4[base], v2 = A4[base + 1];
            float f[12] = {v0.x, v0.y, v0.z, v0.w,
                           v1.x, v1.y, v1.z, v1.w,
                           v2.x, v2.y, v2.z, v2.w};
            float oo[4];
            #pragma unroll
            for (int i = 0; i < 4; ++i) {
                if constexpr (D == 1)
                    oo[i] = k0 * (f[i + 2] + f[i + 6]) + k1 * (f[i + 3] + f[i + 5]) + k2 * f[i + 4];
                else
                    oo[i] = k0 * (f[i]     + f[i + 8]) + k1 * (f[i + 2] + f[i + 6]) + k2 * f[i + 4];
            }
            o.x = oo[0]; o.y = oo[1]; o.z = oo[2]; o.w = oo[3];
        }
        B4[base] = o;
    }
    __syncthreads();

    // ---- vertical 5-tap, 4-row register blocking: B -> A (in place) ----
    // Outputs y, y+D, y+2D, y+3D (same residue class) share 4/5 taps: 8 reads / 4 vec4 outs.
    constexpr int NC = RW / D - 8;       // rows per residue class in [4D, 128-4D)
    constexpr int GR = NC / 4;           // 4-row groups per class
    constexpr int VTASKS = D * GR * Q;
    for (int t = tid; t < VTASKS; t += NT) {
        int q  = t % Q;
        int u  = t / Q;
        int c  = u % D;                  // residue class
        int g  = u / D;                  // group within class
        int qx = D + q;
        float4 rr[8];
        #pragma unroll
        for (int m = 0; m < 8; ++m) {
            int r = 4 * D + c + (4 * g + m - 2) * D;   // htmp rows, all in [2D, 128-2D)
            rr[m] = B4[r * LSV + qx];
        }
        #pragma unroll
        for (int k = 0; k < 4; ++k) {
            float4 acc;
            acc.x = k0 * (rr[k].x + rr[k+4].x) + k1 * (rr[k+1].x + rr[k+3].x) + k2 * rr[k+2].x;
            acc.y = k0 * (rr[k].y + rr[k+4].y) + k1 * (rr[k+1].y + rr[k+3].y) + k2 * rr[k+2].y;
            acc.z = k0 * (rr[k].z + rr[k+4].z) + k1 * (rr[k+1].z + rr[k+3].z) + k2 * rr[k+2].z;
            acc.w = k0 * (rr[k].w + rr[k+4].w) + k1 * (rr[k+1].w + rr[k+3].w) + k2 * rr[k+2].w;
            int r  = 4 * D + c + (4 * g + k) * D;
            int ai = r * LSV + qx;
            int x  = 4 * qx;
            bool center = (r >= HALO) && (r < HALO + TS) && (x >= HALO) && (x < HALO + TS);
            if (center) {
                float4 old = A4[ai];                   // coarse_s (read before overwrite)
                float4 d = {old.x - acc.x, old.y - acc.y, old.z - acc.z, old.w - acc.w};
                long gofs = (long)(by - HALO + r) * W + (bx - HALO + x);
                *(float4*)(det + gofs) = d;
                if constexpr (D == 8) *(float4*)(coa + gofs) = acc;
            }
            A4[ai] = acc;                              // A now holds coarse_{s+1}
        }
    }
    __syncthreads();
}

__global__ __launch_bounds__(NT)
void starlet_fused(const float* __restrict__ in, float* __restrict__ out)
{
    __shared__ float4 Abuf[RW * LSV];
    __shared__ float4 Bbuf[RW * LSV];
    float* A = (float*)Abuf;

    const int tid = threadIdx.x;
    const int bx  = blockIdx.x * TS;
    const int by  = blockIdx.y * TS;
    const int b   = blockIdx.z;
    const float* __restrict__ inp  = in  + (long)b * H * W;
    float* __restrict__       outp = out + (long)b * 5L * H * W;

    // ---- load region [by-32, by+96) x [bx-32, bx+96) into A ----
    const bool interior = (bx >= HALO) && (bx + TS + HALO <= W) &&
                          (by >= HALO) && (by + TS + HALO <= H);
    if (interior) {
        const float* src = inp + (long)(by - HALO) * W + (bx - HALO);
        #pragma unroll
        for (int k = 0; k < 4; ++k) {
            int idx = tid + k * NT;              // 4096 vec4 = 128 rows x 32 vec4
            int r   = idx >> 5;
            int cq  = idx & 31;
            Abuf[r * LSV + cq] = *(const float4*)(src + (long)r * W + 4 * cq);
        }
    } else {
        #pragma unroll
        for (int k = 0; k < 16; ++k) {
            int idx = tid + k * NT;              // 16384 scalar loads with reflect
            int r   = idx >> 7;
            int cc  = idx & 127;
            int gy  = reflect_i(by - HALO + r, H);
            int gx  = reflect_i(bx - HALO + cc, W);
            A[r * (4 * LSV) + cc] = inp[(long)gy * W + gx];
        }
    }
    __syncthreads();

    // cascade: A always holds current coarse; valid region shrinks 2D per side per scale
    scale_pass<1>(Abuf, Bbuf, tid, bx, by, outp + 0L * H * W, nullptr);
    scale_pass<2>(Abuf, Bbuf, tid, bx, by, outp + 1L * H * W, nullptr);
    scale_pass<4>(Abuf, Bbuf, tid, bx, by, outp + 2L * H * W, nullptr);
    scale_pass<8>(Abuf, Bbuf, tid, bx, by, outp + 3L * H * W, outp + 4L * H * W);
}

extern "C" void kernel_launch(void* const* d_in, const int* in_sizes, int n_in,
                              void* d_out, int out_size, void* d_ws, size_t ws_size,
                              hipStream_t stream) {
    const float* x = (const float*)d_in[0];
    float* out = (float*)d_out;
    (void)in_sizes; (void)n_in; (void)d_ws; (void)ws_size; (void)out_size;

    dim3 grid(W / TS, H / TS, 16);
    dim3 block(NT);
    starlet_fused<<<grid, block, 0, stream>>>(x, out);
}